// Round 12
// baseline (764.250 us; speedup 1.0000x reference)
//
#include <hip/hip_runtime.h>

// Gaussian MMD distance as one weighted symmetric quadratic form over
// X = concat(a,b), weights +1/-1; upper-triangular 64x64 tiles only
// (off-diagonal x2). Per element: exp(-0.5*dm^2/vs) * rsqrt(vs).
// R12: v_rsq_f32 (~11 issue-cyc, trans port) replaced by integer-magic
// rsqrt + 1 Newton (full-rate int + pk ops). Newton err <=1.75e-3 is
// smooth; off-diag bias cancels between AA/BB/AB (identical input
// distributions, degenerate V-stat ~4e-7); diag part ~2.7e-6 << 1.26e-5.
// NOTES: (256,8) cap=64 -> acc spills, 5x regression (R4/R6).
//        Restaging LDS while acc is live (R10) -> scratch, 1.3x.
//        ext_vector vs float2 (R9), DSPLIT 16 (R8), cap 128 (R11): null.

#define NTT 32                    // 64-row tiles per dim (2048/64)
#define NTRI (NTT*(NTT+1)/2)      // 528 upper-triangular tiles
#define DSPLIT 8                  // d split: each block does 16 d = 8 pairs
#define NPART (NTRI*DSPLIT)       // 4224 partials
#define PAIRS 8                   // d-pairs staged per block
#define RSTRIDE 9                 // float4 row stride (pad: <=2-way banks)

#define MUSCALE 0.84932180028801904272f   // sqrt(0.5*log2(e))
#define LOG2E   1.4426950408889634f

__device__ __forceinline__ int tri_off(int b) {
  return b * (2 * NTT + 1 - b) / 2;
}

__global__ __launch_bounds__(256, 4) void pair_kernel(
    const float* __restrict__ mu_a, const float* __restrict__ lv_a,
    const float* __restrict__ mu_b, const float* __restrict__ lv_b,
    double* __restrict__ partials)
{
  // [side][row 64][pair 8 + pad]: float4 (mu0*C, mu1*C, var0, var1). 18 KiB.
  __shared__ float4 lds[2][64 * RSTRIDE];
  __shared__ double wsum[4];

  // ---- triangular tile decode: blockIdx.x in [0,528) -> (bi <= bj) ----
  const int k = blockIdx.x;
  int bi = (int)((2.0 * NTT + 1.0
                  - sqrt((2.0 * NTT + 1.0) * (2.0 * NTT + 1.0) - 8.0 * k)) * 0.5);
  if (bi < 0) bi = 0;
  if (bi > NTT - 1) bi = NTT - 1;
  while (tri_off(bi + 1) <= k) ++bi;
  while (tri_off(bi) > k) --bi;
  const int bj = bi + (k - tri_off(bi));

  const int rI = bi * 64, rJ = bj * 64;     // never straddle a/b boundary
  const float* muI = (rI < 1024) ? mu_a + rI * 128 : mu_b + (rI - 1024) * 128;
  const float* lvI = (rI < 1024) ? lv_a + rI * 128 : lv_b + (rI - 1024) * 128;
  const float* muJ = (rJ < 1024) ? mu_a + rJ * 128 : mu_b + (rJ - 1024) * 128;
  const float* lvJ = (rJ < 1024) ? lv_a + rJ * 128 : lv_b + (rJ - 1024) * 128;

  const int tid = threadIdx.x;
  const int dbase = blockIdx.y * (128 / DSPLIT);   // 16 d's per block

  // ---- stage: 1024 float4 slots, 4 per thread, coalesced float2 loads ----
  #pragma unroll
  for (int it = 0; it < 4; ++it) {
    int s = tid + it * 256;            // [0, 1024)
    int side = s >> 9, rem = s & 511;
    int row = rem >> 3, p = rem & 7;
    const float2* m2 = (const float2*)((side == 0) ? muI : muJ);
    const float2* l2 = (const float2*)((side == 0) ? lvI : lvJ);
    int g = row * 64 + (dbase >> 1) + p;
    float2 m = m2[g], l = l2[g];
    lds[side][row * RSTRIDE + p] =
        make_float4(m.x * MUSCALE, m.y * MUSCALE,
                    __builtin_amdgcn_exp2f(l.x * LOG2E),
                    __builtin_amdgcn_exp2f(l.y * LOG2E));
  }
  __syncthreads();

  // ---- compute: 16x16 threads, 4x4 rows x 2 d's per ds_read_b128 ----
  // Row base addrs are loop-invariant; p is a compile-time offset immediate.
  const int tj = tid & 15, ti = tid >> 4;
  const float4* baseA[4];
  const float4* baseB[4];
  #pragma unroll
  for (int q = 0; q < 4; ++q) {
    baseA[q] = &lds[0][(ti + 16 * q) * RSTRIDE];
    baseB[q] = &lds[1][(tj + 16 * q) * RSTRIDE];
  }

  float2 acc[4][4];
  #pragma unroll
  for (int x = 0; x < 4; ++x)
    #pragma unroll
    for (int y = 0; y < 4; ++y) acc[x][y] = make_float2(0.f, 0.f);

  #pragma unroll
  for (int p = 0; p < PAIRS; ++p) {
    float4 A[4], B[4];
    #pragma unroll
    for (int q = 0; q < 4; ++q) {
      A[q] = baseA[q][p];          // ds_read_b128 ..., offset:p*16
      B[q] = baseB[q][p];
    }
    #pragma unroll
    for (int x = 0; x < 4; ++x) {
      const float2 Amu = make_float2(A[x].x, A[x].y);
      const float2 Avr = make_float2(A[x].z, A[x].w);
      #pragma unroll
      for (int y = 0; y < 4; ++y) {
        const float2 Bmu = make_float2(B[y].x, B[y].y);
        const float2 Bvr = make_float2(B[y].z, B[y].w);
        float2 vs = Avr + Bvr;                       // v_pk_add_f32
        // ---- magic rsqrt + 1 Newton (full-rate, no trans port) ----
        float2 r0;
        r0.x = __uint_as_float(0x5F3759DFu - (__float_as_uint(vs.x) >> 1));
        r0.y = __uint_as_float(0x5F3759DFu - (__float_as_uint(vs.y) >> 1));
        float2 hvs = vs * 0.5f;                      // v_pk_mul_f32
        float2 s2  = r0 * r0;                        // v_pk_mul_f32
        float2 u;                                    // 1.5 - hvs*s2
        u.x = fmaf(-hvs.x, s2.x, 1.5f);              // v_pk_fma_f32 (neg)
        u.y = fmaf(-hvs.y, s2.y, 1.5f);
        float2 r = r0 * u;                           // v_pk_mul_f32
        // -----------------------------------------------------------
        float2 dm = Amu - Bmu;                       // v_pk_add_f32 (neg)
        float2 t  = dm * r;                          // v_pk_mul_f32
        float2 m  = t * t;                           // v_pk_mul_f32
        float2 e;
        e.x = __builtin_amdgcn_exp2f(-m.x);          // v_exp_f32 [trans]
        e.y = __builtin_amdgcn_exp2f(-m.y);
        acc[x][y].x = fmaf(e.x, r.x, acc[x][y].x);   // v_pk_fma_f32
        acc[x][y].y = fmaf(e.y, r.y, acc[x][y].y);
      }
    }
  }

  // ---- reduction: f32 pairwise -> f64 (cancellation safety) ----
  float2 s0 = make_float2(0.f, 0.f), s1 = make_float2(0.f, 0.f);
  #pragma unroll
  for (int x = 0; x < 4; ++x) {
    s0 += acc[x][0] + acc[x][1];
    s1 += acc[x][2] + acc[x][3];
  }
  double pdb = (double)(s0.x + s1.x) + (double)(s0.y + s1.y);
  for (int off = 32; off > 0; off >>= 1) pdb += __shfl_down(pdb, off, 64);

  if ((tid & 63) == 0) wsum[tid >> 6] = pdb;
  __syncthreads();
  if (tid == 0) {
    double t = (wsum[0] + wsum[1]) + (wsum[2] + wsum[3]);
    double w = ((bi < 16) == (bj < 16)) ? 1.0 : -1.0;   // sign s_I*s_J
    if (bi != bj) w *= 2.0;                              // symmetry factor
    partials[blockIdx.y * NTRI + blockIdx.x] = w * t;
  }
}

__global__ __launch_bounds__(1024) void final_reduce(
    const double* __restrict__ partials, float* __restrict__ out)
{
  __shared__ double wsum[16];
  double s = 0.0;
  for (int i = threadIdx.x; i < NPART; i += 1024) s += partials[i];
  for (int off = 32; off > 0; off >>= 1) s += __shfl_down(s, off, 64);
  if ((threadIdx.x & 63) == 0) wsum[threadIdx.x >> 6] = s;
  __syncthreads();
  if (threadIdx.x == 0) {
    double t = 0.0;
    #pragma unroll
    for (int wv = 0; wv < 16; ++wv) t += wsum[wv];
    out[0] = (float)(t * (1.0 / (1024.0 * 1024.0 * 128.0)));
  }
}

extern "C" void kernel_launch(void* const* d_in, const int* in_sizes, int n_in,
                              void* d_out, int out_size, void* d_ws, size_t ws_size,
                              hipStream_t stream) {
  const float* mu_a = (const float*)d_in[0];
  const float* lv_a = (const float*)d_in[1];
  const float* mu_b = (const float*)d_in[2];
  const float* lv_b = (const float*)d_in[3];
  float* out = (float*)d_out;
  double* partials = (double*)d_ws;   // NPART*8 = 33 KiB scratch

  dim3 grid(NTRI, DSPLIT);
  pair_kernel<<<grid, 256, 0, stream>>>(mu_a, lv_a, mu_b, lv_b, partials);
  final_reduce<<<1, 1024, 0, stream>>>(partials, out);
}

// Round 13
// 80.450 us; speedup vs baseline: 9.4997x; 9.4997x over previous
//
#include <hip/hip_runtime.h>

// Gaussian MMD distance as one weighted symmetric quadratic form over
// X = concat(a,b), weights +1/-1; upper-triangular 64x64 tiles only
// (off-diagonal x2). Per element: exp(-0.5*dm^2/vs) * rsqrt(vs).
// R13: magic-rsqrt + 1 Newton (R12's math: measured absmax 3.8e-6, 3.3x
// under threshold) with the compiler cliff removed: p-loop unroll 2 (not
// 8) and NO arrays in the hot loop (named regs only) so nothing can be
// demoted to scratch (R12: localMem arrays -> 1.5GB scratch, 12x).
// NOTES: (256,8) cap=64 -> acc spills (R4/R6). Restage w/ live acc (R10):
// scratch. ext_vector (R9), DSPLIT16 (R8), cap128 alone (R11): null.

#define NTT 32                    // 64-row tiles per dim (2048/64)
#define NTRI (NTT*(NTT+1)/2)      // 528 upper-triangular tiles
#define DSPLIT 8                  // d split: each block does 16 d = 8 pairs
#define NPART (NTRI*DSPLIT)       // 4224 partials
#define PAIRS 8                   // d-pairs staged per block
#define RSTRIDE 9                 // float4 row stride (pad: <=2-way banks)

#define MUSCALE 0.84932180028801904272f   // sqrt(0.5*log2(e))
#define LOG2E   1.4426950408889634f

__device__ __forceinline__ int tri_off(int b) {
  return b * (2 * NTT + 1 - b) / 2;
}

__device__ __forceinline__ void cell(const float4& A, const float4& B,
                                     float2& acc) {
  float2 vs;
  vs.x = A.z + B.z;  vs.y = A.w + B.w;               // v_pk_add_f32
  // magic rsqrt + 1 Newton (full-rate; avoids the quarter-rate trans port)
  float2 r0;
  r0.x = __uint_as_float(0x5F3759DFu - (__float_as_uint(vs.x) >> 1));
  r0.y = __uint_as_float(0x5F3759DFu - (__float_as_uint(vs.y) >> 1));
  float2 u;
  u.x = fmaf(vs.x * -0.5f, r0.x * r0.x, 1.5f);
  u.y = fmaf(vs.y * -0.5f, r0.y * r0.y, 1.5f);
  float2 r;
  r.x = r0.x * u.x;  r.y = r0.y * u.y;               // v_pk_mul_f32
  float2 dm;
  dm.x = A.x - B.x;  dm.y = A.y - B.y;               // v_pk_add_f32
  float2 t;
  t.x = dm.x * r.x;  t.y = dm.y * r.y;               // v_pk_mul_f32
  float2 e;
  e.x = __builtin_amdgcn_exp2f(-(t.x * t.x));        // v_exp_f32 [trans]
  e.y = __builtin_amdgcn_exp2f(-(t.y * t.y));
  acc.x = fmaf(e.x, r.x, acc.x);                     // v_pk_fma_f32
  acc.y = fmaf(e.y, r.y, acc.y);
}

__global__ __launch_bounds__(256, 4) void pair_kernel(
    const float* __restrict__ mu_a, const float* __restrict__ lv_a,
    const float* __restrict__ mu_b, const float* __restrict__ lv_b,
    double* __restrict__ partials)
{
  // [side][row 64][pair 8 + pad]: float4 (mu0*C, mu1*C, var0, var1). 18 KiB.
  __shared__ float4 lds[2][64 * RSTRIDE];
  __shared__ double wsum[4];

  // ---- triangular tile decode: blockIdx.x in [0,528) -> (bi <= bj) ----
  const int k = blockIdx.x;
  int bi = (int)((2.0 * NTT + 1.0
                  - sqrt((2.0 * NTT + 1.0) * (2.0 * NTT + 1.0) - 8.0 * k)) * 0.5);
  if (bi < 0) bi = 0;
  if (bi > NTT - 1) bi = NTT - 1;
  while (tri_off(bi + 1) <= k) ++bi;
  while (tri_off(bi) > k) --bi;
  const int bj = bi + (k - tri_off(bi));

  const int rI = bi * 64, rJ = bj * 64;     // never straddle a/b boundary
  const float* muI = (rI < 1024) ? mu_a + rI * 128 : mu_b + (rI - 1024) * 128;
  const float* lvI = (rI < 1024) ? lv_a + rI * 128 : lv_b + (rI - 1024) * 128;
  const float* muJ = (rJ < 1024) ? mu_a + rJ * 128 : mu_b + (rJ - 1024) * 128;
  const float* lvJ = (rJ < 1024) ? lv_a + rJ * 128 : lv_b + (rJ - 1024) * 128;

  const int tid = threadIdx.x;
  const int dbase = blockIdx.y * (128 / DSPLIT);   // 16 d's per block

  // ---- stage: 1024 float4 slots, 4 per thread, coalesced float2 loads ----
  #pragma unroll
  for (int it = 0; it < 4; ++it) {
    int s = tid + it * 256;            // [0, 1024)
    int side = s >> 9, rem = s & 511;
    int row = rem >> 3, p = rem & 7;
    const float2* m2 = (const float2*)((side == 0) ? muI : muJ);
    const float2* l2 = (const float2*)((side == 0) ? lvI : lvJ);
    int g = row * 64 + (dbase >> 1) + p;
    float2 m = m2[g], l = l2[g];
    lds[side][row * RSTRIDE + p] =
        make_float4(m.x * MUSCALE, m.y * MUSCALE,
                    __builtin_amdgcn_exp2f(l.x * LOG2E),
                    __builtin_amdgcn_exp2f(l.y * LOG2E));
  }
  __syncthreads();

  // ---- compute: 16x16 threads, 4x4 rows x 2 d's per ds_read_b128 ----
  const int tj = tid & 15, ti = tid >> 4;
  const float4* pA0 = &lds[0][(ti +  0) * RSTRIDE];
  const float4* pA1 = &lds[0][(ti + 16) * RSTRIDE];
  const float4* pA2 = &lds[0][(ti + 32) * RSTRIDE];
  const float4* pA3 = &lds[0][(ti + 48) * RSTRIDE];
  const float4* pB0 = &lds[1][(tj +  0) * RSTRIDE];
  const float4* pB1 = &lds[1][(tj + 16) * RSTRIDE];
  const float4* pB2 = &lds[1][(tj + 32) * RSTRIDE];
  const float4* pB3 = &lds[1][(tj + 48) * RSTRIDE];

  float2 a00 = {0,0}, a01 = {0,0}, a02 = {0,0}, a03 = {0,0};
  float2 a10 = {0,0}, a11 = {0,0}, a12 = {0,0}, a13 = {0,0};
  float2 a20 = {0,0}, a21 = {0,0}, a22 = {0,0}, a23 = {0,0};
  float2 a30 = {0,0}, a31 = {0,0}, a32 = {0,0}, a33 = {0,0};

  #pragma unroll 2
  for (int p = 0; p < PAIRS; ++p) {
    const float4 A0 = pA0[p], A1 = pA1[p], A2 = pA2[p], A3 = pA3[p];
    const float4 B0 = pB0[p], B1 = pB1[p], B2 = pB2[p], B3 = pB3[p];
    cell(A0, B0, a00); cell(A0, B1, a01); cell(A0, B2, a02); cell(A0, B3, a03);
    cell(A1, B0, a10); cell(A1, B1, a11); cell(A1, B2, a12); cell(A1, B3, a13);
    cell(A2, B0, a20); cell(A2, B1, a21); cell(A2, B2, a22); cell(A2, B3, a23);
    cell(A3, B0, a30); cell(A3, B1, a31); cell(A3, B2, a32); cell(A3, B3, a33);
  }

  // ---- reduction: f32 pairwise -> f64 (cancellation safety) ----
  float2 s0 = (a00 + a01) + (a02 + a03);
  float2 s1 = (a10 + a11) + (a12 + a13);
  float2 s2 = (a20 + a21) + (a22 + a23);
  float2 s3 = (a30 + a31) + (a32 + a33);
  float2 st = (s0 + s1) + (s2 + s3);
  double pdb = (double)st.x + (double)st.y;
  for (int off = 32; off > 0; off >>= 1) pdb += __shfl_down(pdb, off, 64);

  if ((tid & 63) == 0) wsum[tid >> 6] = pdb;
  __syncthreads();
  if (tid == 0) {
    double t = (wsum[0] + wsum[1]) + (wsum[2] + wsum[3]);
    double w = ((bi < 16) == (bj < 16)) ? 1.0 : -1.0;   // sign s_I*s_J
    if (bi != bj) w *= 2.0;                              // symmetry factor
    partials[blockIdx.y * NTRI + blockIdx.x] = w * t;
  }
}

__global__ __launch_bounds__(1024) void final_reduce(
    const double* __restrict__ partials, float* __restrict__ out)
{
  __shared__ double wsum[16];
  double s = 0.0;
  for (int i = threadIdx.x; i < NPART; i += 1024) s += partials[i];
  for (int off = 32; off > 0; off >>= 1) s += __shfl_down(s, off, 64);
  if ((threadIdx.x & 63) == 0) wsum[threadIdx.x >> 6] = s;
  __syncthreads();
  if (threadIdx.x == 0) {
    double t = 0.0;
    #pragma unroll
    for (int wv = 0; wv < 16; ++wv) t += wsum[wv];
    out[0] = (float)(t * (1.0 / (1024.0 * 1024.0 * 128.0)));
  }
}

extern "C" void kernel_launch(void* const* d_in, const int* in_sizes, int n_in,
                              void* d_out, int out_size, void* d_ws, size_t ws_size,
                              hipStream_t stream) {
  const float* mu_a = (const float*)d_in[0];
  const float* lv_a = (const float*)d_in[1];
  const float* mu_b = (const float*)d_in[2];
  const float* lv_b = (const float*)d_in[3];
  float* out = (float*)d_out;
  double* partials = (double*)d_ws;   // NPART*8 = 33 KiB scratch

  dim3 grid(NTRI, DSPLIT);
  pair_kernel<<<grid, 256, 0, stream>>>(mu_a, lv_a, mu_b, lv_b, partials);
  final_reduce<<<1, 1024, 0, stream>>>(partials, out);
}

// Round 14
// 64.413 us; speedup vs baseline: 11.8648x; 1.2490x over previous
//
#include <hip/hip_runtime.h>

// Gaussian MMD distance as one weighted symmetric quadratic form over
// X = concat(a,b), weights +1/-1; upper-triangular 64x64 tiles only
// (off-diagonal x2). Per element: exp(-0.5*dm^2/vs) * rsqrt(vs).
// Issue-port roofline: min stream = 5 pk (10cyc) + 4 trans (~47cyc) per
// 2-elem cell => ~50us busy (measured, invariant R3-R13). Wall 62.7 at
// ~80% port util. R14: DSPLIT 4 (32 d/block, 2112 blocks) — halve the
// per-element stage/barrier/block-start overhead (R7>R8 direction).
// NOTES: magic-rsqrt costs MORE issue than v_rsq (R13: busy 50->78us).
// (256,8) cap=64 spills acc (R4/R6). Restage w/ live acc (R10): scratch.
// Full unroll of big p-loops demotes arrays to scratch (R12, 12x).

#define NTT 32                    // 64-row tiles per dim (2048/64)
#define NTRI (NTT*(NTT+1)/2)      // 528 upper-triangular tiles
#define DSPLIT 4                  // d split: each block does 32 d = 16 pairs
#define NPART (NTRI*DSPLIT)       // 2112 partials
#define PAIRS 16                  // d-pairs staged per block
#define RSTRIDE 17                // float4 row stride (pad: 2-way banks, free)

#define MUSCALE 0.84932180028801904272f   // sqrt(0.5*log2(e))
#define LOG2E   1.4426950408889634f

__device__ __forceinline__ int tri_off(int b) {
  return b * (2 * NTT + 1 - b) / 2;
}

__global__ __launch_bounds__(256, 4) void pair_kernel(
    const float* __restrict__ mu_a, const float* __restrict__ lv_a,
    const float* __restrict__ mu_b, const float* __restrict__ lv_b,
    double* __restrict__ partials)
{
  // [side][row 64][pair 16 + pad]: float4 (mu0*C, mu1*C, var0, var1). 34 KiB.
  __shared__ float4 lds[2][64 * RSTRIDE];
  __shared__ double wsum[4];

  // ---- triangular tile decode: blockIdx.x in [0,528) -> (bi <= bj) ----
  const int k = blockIdx.x;
  int bi = (int)((2.0 * NTT + 1.0
                  - sqrt((2.0 * NTT + 1.0) * (2.0 * NTT + 1.0) - 8.0 * k)) * 0.5);
  if (bi < 0) bi = 0;
  if (bi > NTT - 1) bi = NTT - 1;
  while (tri_off(bi + 1) <= k) ++bi;
  while (tri_off(bi) > k) --bi;
  const int bj = bi + (k - tri_off(bi));

  const int rI = bi * 64, rJ = bj * 64;     // never straddle a/b boundary
  const float* muI = (rI < 1024) ? mu_a + rI * 128 : mu_b + (rI - 1024) * 128;
  const float* lvI = (rI < 1024) ? lv_a + rI * 128 : lv_b + (rI - 1024) * 128;
  const float* muJ = (rJ < 1024) ? mu_a + rJ * 128 : mu_b + (rJ - 1024) * 128;
  const float* lvJ = (rJ < 1024) ? lv_a + rJ * 128 : lv_b + (rJ - 1024) * 128;

  const int tid = threadIdx.x;
  const int dbase = blockIdx.y * (128 / DSPLIT);   // 32 d's per block

  // ---- stage: 2048 float4 slots, 8 per thread, coalesced float2 loads ----
  #pragma unroll
  for (int it = 0; it < 8; ++it) {
    int s = tid + it * 256;            // [0, 2048)
    int side = s >> 10, rem = s & 1023;
    int row = rem >> 4, p = rem & 15;
    const float2* m2 = (const float2*)((side == 0) ? muI : muJ);
    const float2* l2 = (const float2*)((side == 0) ? lvI : lvJ);
    int g = row * 64 + (dbase >> 1) + p;
    float2 m = m2[g], l = l2[g];
    lds[side][row * RSTRIDE + p] =
        make_float4(m.x * MUSCALE, m.y * MUSCALE,
                    __builtin_amdgcn_exp2f(l.x * LOG2E),
                    __builtin_amdgcn_exp2f(l.y * LOG2E));
  }
  __syncthreads();

  // ---- compute: 16x16 threads, 4x4 rows x 2 d's per ds_read_b128 ----
  // Row base addrs are loop-invariant; p is a ds_read offset immediate.
  const int tj = tid & 15, ti = tid >> 4;
  const float4* baseA[4];
  const float4* baseB[4];
  #pragma unroll
  for (int q = 0; q < 4; ++q) {
    baseA[q] = &lds[0][(ti + 16 * q) * RSTRIDE];
    baseB[q] = &lds[1][(tj + 16 * q) * RSTRIDE];
  }

  float2 acc[4][4];
  #pragma unroll
  for (int x = 0; x < 4; ++x)
    #pragma unroll
    for (int y = 0; y < 4; ++y) acc[x][y] = make_float2(0.f, 0.f);

  #pragma unroll 2
  for (int p = 0; p < PAIRS; ++p) {
    float4 A[4], B[4];
    #pragma unroll
    for (int q = 0; q < 4; ++q) {
      A[q] = baseA[q][p];          // ds_read_b128 ..., offset:p*16
      B[q] = baseB[q][p];
    }
    #pragma unroll
    for (int x = 0; x < 4; ++x) {
      const float2 Amu = make_float2(A[x].x, A[x].y);
      const float2 Avr = make_float2(A[x].z, A[x].w);
      #pragma unroll
      for (int y = 0; y < 4; ++y) {
        const float2 Bmu = make_float2(B[y].x, B[y].y);
        const float2 Bvr = make_float2(B[y].z, B[y].w);
        float2 vs = Avr + Bvr;                       // v_pk_add_f32
        float2 r;
        r.x = __builtin_amdgcn_rsqf(vs.x);           // v_rsq_f32 [trans]
        r.y = __builtin_amdgcn_rsqf(vs.y);
        float2 dm = Amu - Bmu;                       // v_pk_add_f32 (neg)
        float2 t  = dm * r;                          // v_pk_mul_f32
        float2 m  = t * t;                           // v_pk_mul_f32
        float2 e;
        e.x = __builtin_amdgcn_exp2f(-m.x);          // v_exp_f32 [trans]
        e.y = __builtin_amdgcn_exp2f(-m.y);
        acc[x][y] += e * r;                          // v_pk_fma_f32
      }
    }
  }

  // ---- reduction: f32 pairwise -> f64 (cancellation safety) ----
  float2 s0 = make_float2(0.f, 0.f), s1 = make_float2(0.f, 0.f);
  #pragma unroll
  for (int x = 0; x < 4; ++x) {
    s0 += acc[x][0] + acc[x][1];
    s1 += acc[x][2] + acc[x][3];
  }
  double pdb = (double)(s0.x + s1.x) + (double)(s0.y + s1.y);
  for (int off = 32; off > 0; off >>= 1) pdb += __shfl_down(pdb, off, 64);

  if ((tid & 63) == 0) wsum[tid >> 6] = pdb;
  __syncthreads();
  if (tid == 0) {
    double t = (wsum[0] + wsum[1]) + (wsum[2] + wsum[3]);
    double w = ((bi < 16) == (bj < 16)) ? 1.0 : -1.0;   // sign s_I*s_J
    if (bi != bj) w *= 2.0;                              // symmetry factor
    partials[blockIdx.y * NTRI + blockIdx.x] = w * t;
  }
}

__global__ __launch_bounds__(1024) void final_reduce(
    const double* __restrict__ partials, float* __restrict__ out)
{
  __shared__ double wsum[16];
  double s = 0.0;
  for (int i = threadIdx.x; i < NPART; i += 1024) s += partials[i];
  for (int off = 32; off > 0; off >>= 1) s += __shfl_down(s, off, 64);
  if ((threadIdx.x & 63) == 0) wsum[threadIdx.x >> 6] = s;
  __syncthreads();
  if (threadIdx.x == 0) {
    double t = 0.0;
    #pragma unroll
    for (int wv = 0; wv < 16; ++wv) t += wsum[wv];
    out[0] = (float)(t * (1.0 / (1024.0 * 1024.0 * 128.0)));
  }
}

extern "C" void kernel_launch(void* const* d_in, const int* in_sizes, int n_in,
                              void* d_out, int out_size, void* d_ws, size_t ws_size,
                              hipStream_t stream) {
  const float* mu_a = (const float*)d_in[0];
  const float* lv_a = (const float*)d_in[1];
  const float* mu_b = (const float*)d_in[2];
  const float* lv_b = (const float*)d_in[3];
  float* out = (float*)d_out;
  double* partials = (double*)d_ws;   // NPART*8 = 16.5 KiB scratch

  dim3 grid(NTRI, DSPLIT);
  pair_kernel<<<grid, 256, 0, stream>>>(mu_a, lv_a, mu_b, lv_b, partials);
  final_reduce<<<1, 1024, 0, stream>>>(partials, out);
}